// Round 1
// 2826.285 us; speedup vs baseline: 1.2553x; 1.2553x over previous
//
#include <hip/hip_runtime.h>
#include <hip/hip_fp16.h>
#include <stdint.h>

typedef _Float16 f16;
typedef _Float16 f16x8 __attribute__((ext_vector_type(8)));
typedef _Float16 f16x4 __attribute__((ext_vector_type(4)));
typedef float    f32x4 __attribute__((ext_vector_type(4)));

#define MFMA16(a, b, c) __builtin_amdgcn_mfma_f32_16x16x32_f16((a), (b), (c), 0, 0, 0)

// ---- problem dims ----
static constexpr int N1P = 1152;   // enc layer-1 N (1056) padded to 9*128

// ---- workspace layout (bytes, all 256-aligned) ----
static constexpr size_t OFF_FLAGS = 0;                                    // 4 KiB counters
static constexpr size_t OFF_XT    = 4096;                                 // f16 [64][257][1024] (row 0 = zeros = prev at t=0)
static constexpr size_t OFF_WE1T  = OFF_XT   + (size_t)64 * 257 * 1024 * 2;  // f16 [1152][2048]
static constexpr size_t OFF_WE2T  = OFF_WE1T + (size_t)1152 * 2048 * 2;      // f16 [64][1152]
static constexpr size_t OFF_WD1T  = OFF_WE2T + (size_t)64 * 1152 * 2;        // f16 [1056][1088]
static constexpr size_t OFF_WD2T  = OFF_WD1T + (size_t)1056 * 1088 * 2;      // f16 [1024][1056]
static constexpr size_t OFF_HENC  = OFF_WD2T + (size_t)1024 * 1056 * 2;      // f16 [16384][1152]; decoder reuses as hG[256][64][1056]
static constexpr size_t OFF_CTRL  = OFF_HENC + (size_t)16384 * 1152 * 2;     // f16 [256][64][64]
static constexpr size_t OFF_ST    = OFF_CTRL + (size_t)256 * 64 * 64 * 2;    // f16 [256][64][1024] (decoder outputs)
static constexpr size_t OFF_HG    = OFF_ST   + (size_t)256 * 64 * 1024 * 2;  // (legacy, unused)
static constexpr size_t WS_NEED   = OFF_HG   + (size_t)64 * 1056 * 2;

// decoder LDS: Wd1 slice [32][1096] + Wd2 slice [32][1064] (padded strides)
static constexpr int SW1S = 1096, SW2S = 1064;
static constexpr size_t DEC_LDS = (size_t)32 * (SW1S + SW2S) * 2;  // 138240

// =============================== prep kernels ===============================

__global__ __launch_bounds__(256) void k_zero_x0(f16* __restrict__ xT) {
  f16x4 z = {};
  *(f16x4*)(xT + (size_t)blockIdx.x * 257 * 1024 + threadIdx.x * 4) = z;
}

// x [64][1024][256] f32  ->  xT[b][t+1][s] f16   (xT row 0 stays zero)
__global__ __launch_bounds__(256) void k_transpose_x(const float* __restrict__ x,
                                                     f16* __restrict__ xT) {
  __shared__ float tile[32][33];
  int b = blockIdx.z, s0 = blockIdx.x * 32, t0 = blockIdx.y * 32;
  int r = threadIdx.x >> 3, c4 = (threadIdx.x & 7) * 4;
  const float4 v = *(const float4*)(x + ((size_t)b * 1024 + s0 + r) * 256 + t0 + c4);
  tile[r][c4 + 0] = v.x; tile[r][c4 + 1] = v.y;
  tile[r][c4 + 2] = v.z; tile[r][c4 + 3] = v.w;
  __syncthreads();
  f16x4 o;
  o[0] = (f16)tile[c4 + 0][r]; o[1] = (f16)tile[c4 + 1][r];
  o[2] = (f16)tile[c4 + 2][r]; o[3] = (f16)tile[c4 + 3][r];
  *(f16x4*)(xT + ((size_t)b * 257 + t0 + r + 1) * 1024 + s0 + c4) = o;
}

// in [K][N] f32 -> out [Npad][Kpad] f16 (zero pad where k>=K or n>=N)
__global__ __launch_bounds__(256) void k_transpose_w(const float* __restrict__ in,
                                                     f16* __restrict__ out,
                                                     int K, int N, int Kpad, int Npad) {
  __shared__ float tile[32][33];
  int k0 = blockIdx.x * 32, n0 = blockIdx.y * 32;
  int r = threadIdx.x >> 3, c4 = (threadIdx.x & 7) * 4;
#pragma unroll
  for (int i = 0; i < 4; i++) {
    int k = k0 + r, n = n0 + c4 + i;
    tile[r][c4 + i] = (k < K && n < N) ? in[(size_t)k * N + n] : 0.f;
  }
  __syncthreads();
  int n = n0 + r;
  if (n < Npad) {
    f16x4 o;
    o[0] = (f16)tile[c4 + 0][r]; o[1] = (f16)tile[c4 + 1][r];
    o[2] = (f16)tile[c4 + 2][r]; o[3] = (f16)tile[c4 + 3][r];
    *(f16x4*)(out + (size_t)n * Kpad + k0 + c4) = o;
  }
}

// =============================== encoder ===============================
__global__ __launch_bounds__(256) void k_enc1(const f16* __restrict__ xT,
                                              const f16* __restrict__ We1T,
                                              const float* __restrict__ be1,
                                              f16* __restrict__ Henc) {
  __shared__ f16 sA[128 * 40];
  __shared__ f16 sB[128 * 40];
  int m0 = blockIdx.x * 128, n0 = blockIdx.y * 128;
  int b = m0 >> 8, t0 = m0 & 255;
  int tid = threadIdx.x, w = tid >> 6, l = tid & 63;
  int wm = (w >> 1) * 64, wn = (w & 1) * 64;
  int lr = l & 15, lq = l >> 4;
  f32x4 acc[4][4] = {};
  for (int kt = 0; kt < 64; kt++) {
    int k0 = kt * 32;
    __syncthreads();
    int tshift = (k0 < 1024) ? 0 : 1;
    int ks = (k0 < 1024) ? k0 : (k0 - 1024);
    int idx = tid;
#pragma unroll
    for (int rep = 0; rep < 2; rep++, idx += 256) {
      int r = idx >> 2, c = idx & 3;
      *(uint4*)(&sA[r * 40 + c * 8]) =
          *(const uint4*)(xT + ((size_t)(b * 257 + t0 + r + tshift)) * 1024 + ks + c * 8);
      *(uint4*)(&sB[r * 40 + c * 8]) =
          *(const uint4*)(We1T + ((size_t)(n0 + r)) * 2048 + k0 + c * 8);
    }
    __syncthreads();
    f16x8 a[4], bb[4];
#pragma unroll
    for (int i = 0; i < 4; i++) a[i] = *(const f16x8*)(&sA[(wm + i * 16 + lr) * 40 + lq * 8]);
#pragma unroll
    for (int j = 0; j < 4; j++) bb[j] = *(const f16x8*)(&sB[(wn + j * 16 + lr) * 40 + lq * 8]);
#pragma unroll
    for (int i = 0; i < 4; i++)
#pragma unroll
      for (int j = 0; j < 4; j++) acc[i][j] = MFMA16(a[i], bb[j], acc[i][j]);
  }
#pragma unroll
  for (int j = 0; j < 4; j++) {
    int n = n0 + wn + j * 16 + lr;
    float bias = (n < 1056) ? be1[n] : 0.f;
#pragma unroll
    for (int i = 0; i < 4; i++) {
#pragma unroll
      for (int rr = 0; rr < 4; rr++) {
        int m = m0 + wm + i * 16 + lq * 4 + rr;
        float v = acc[i][j][rr] + bias;
        v = v > 0.f ? v : 0.f;
        Henc[(size_t)m * N1P + n] = (f16)v;
      }
    }
  }
}

__global__ __launch_bounds__(256) void k_enc2(const f16* __restrict__ Henc,
                                              const f16* __restrict__ We2T,
                                              const float* __restrict__ be2,
                                              f16* __restrict__ ctrl) {
  __shared__ f16 sA[128 * 40];
  __shared__ f16 sB[64 * 40];
  int m0 = blockIdx.x * 128;
  int tid = threadIdx.x, w = tid >> 6, l = tid & 63;
  int wm = w * 32;
  int lr = l & 15, lq = l >> 4;
  f32x4 acc[2][4] = {};
  for (int kt = 0; kt < 36; kt++) {
    int k0 = kt * 32;
    __syncthreads();
    int idx = tid;
#pragma unroll
    for (int rep = 0; rep < 2; rep++, idx += 256) {
      int r = idx >> 2, c = idx & 3;
      *(uint4*)(&sA[r * 40 + c * 8]) =
          *(const uint4*)(Henc + (size_t)(m0 + r) * N1P + k0 + c * 8);
    }
    {
      int r = tid >> 2, c = tid & 3;
      *(uint4*)(&sB[r * 40 + c * 8]) =
          *(const uint4*)(We2T + (size_t)r * N1P + k0 + c * 8);
    }
    __syncthreads();
    f16x8 a[2], bb[4];
#pragma unroll
    for (int i = 0; i < 2; i++) a[i] = *(const f16x8*)(&sA[(wm + i * 16 + lr) * 40 + lq * 8]);
#pragma unroll
    for (int j = 0; j < 4; j++) bb[j] = *(const f16x8*)(&sB[(j * 16 + lr) * 40 + lq * 8]);
#pragma unroll
    for (int i = 0; i < 2; i++)
#pragma unroll
      for (int j = 0; j < 4; j++) acc[i][j] = MFMA16(a[i], bb[j], acc[i][j]);
  }
#pragma unroll
  for (int j = 0; j < 4; j++) {
    int n = j * 16 + lr;
    float bias = be2[n];
#pragma unroll
    for (int i = 0; i < 2; i++) {
#pragma unroll
      for (int rr = 0; rr < 4; rr++) {
        int m = m0 + wm + i * 16 + lq * 4 + rr;
        int bb_ = m >> 8, t = m & 255;
        ctrl[((size_t)t * 64 + bb_) * 64 + n] = (f16)(acc[i][j][rr] + bias);
      }
    }
  }
}

// =============================== decoder ===============================
// Write-through f16 store: bypasses L1/L2, lands at the device coherence
// point (MALL) -> no release fence (buffer_wbl2) ever needed.
__device__ __forceinline__ void st_f16_wt(f16* p, float v) {
  f16 h = (f16)v;
  unsigned u = (unsigned)__builtin_bit_cast(unsigned short, h);
  asm volatile("global_store_short %0, %1, off sc0 sc1" :: "v"(p), "v"(u) : "memory");
}

// grid = 66 blocks: 2 groups (32 batch rows each) x 33 column-slice blocks.
// Fence-free exchange: producers write-through (sc0 sc1) then bump a relaxed
// agent-scope counter; consumers spin on the counter and read with PLAIN
// cached loads — safe because every exchanged address (states[t], hG[t]) is
// t-indexed and touched at most once per dispatch (first-touch after flag),
// and the runtime invalidates L1/L2 at dispatch boundaries.
__global__ __launch_bounds__(256, 1) void k_decoder(
    const f16* __restrict__ ctrl, const f16* __restrict__ Wd1T,
    const f16* __restrict__ Wd2T, const float* __restrict__ bd1,
    const float* __restrict__ bd2, f16* __restrict__ states,
    f16* __restrict__ hG, unsigned* __restrict__ flags) {
  extern __shared__ f16 smem[];
  f16* sW1 = smem;
  f16* sW2 = smem + 32 * SW1S;
  int blk = blockIdx.x;
  int g = blk / 33, j = blk % 33;
  int r0 = g * 32, n0 = j * 32;
  int tid = threadIdx.x, w = tid >> 6, l = tid & 63;
  int lr = l & 15, lq = l >> 4;
  int mt = w >> 1, nt = w & 1;

  // pin weight column-slices in LDS
  for (int idx = tid; idx < 32 * 136; idx += 256) {
    int c = idx / 136, q = idx % 136;
    *(uint4*)(&sW1[c * SW1S + q * 8]) = *(const uint4*)(Wd1T + (size_t)(n0 + c) * 1088 + q * 8);
  }
  if (j < 32) {
    for (int idx = tid; idx < 32 * 132; idx += 256) {
      int c = idx / 132, q = idx % 132;
      *(uint4*)(&sW2[c * SW2S + q * 8]) = *(const uint4*)(Wd2T + (size_t)(n0 + c) * 1056 + q * 8);
    }
  }
  __syncthreads();

  unsigned* cnt = flags + g * 512;   // cnt[2t] = h-ready count, cnt[2t+1] = states-ready count
  int row_b = r0 + mt * 16 + lr;     // this lane's A row (global batch index)
  int wrow = nt * 16 + lr;           // this lane's B column (local)
  float bias1 = bd1[n0 + wrow];
  float bias2 = (j < 32) ? bd2[n0 + wrow] : 0.f;

  for (int t = 0; t < 256; t++) {
    // ---- GEMM1: h_slice = relu(inp @ Wd1_slice + bd1) ----
    // ctrl part has no cross-step dependency: issue before the wait.
    f32x4 acc[4] = {};
    const f16* ctrlRow = ctrl + ((size_t)t * 64 + row_b) * 64;
    {
      f16x8 a0 = *(const f16x8*)(ctrlRow + lq * 8);
      f16x8 b0 = *(const f16x8*)(&sW1[wrow * SW1S + lq * 8]);
      acc[0] = MFMA16(a0, b0, acc[0]);
      f16x8 a1 = *(const f16x8*)(ctrlRow + 32 + lq * 8);
      f16x8 b1 = *(const f16x8*)(&sW1[wrow * SW1S + 32 + lq * 8]);
      acc[1] = MFMA16(a1, b1, acc[1]);
    }
    if (t > 0) {
      if (tid == 0) {
        while (__hip_atomic_load(&cnt[(t - 1) * 2 + 1], __ATOMIC_RELAXED,
                                 __HIP_MEMORY_SCOPE_AGENT) < 32u)
          __builtin_amdgcn_s_sleep(1);
      }
      __syncthreads();
      const f16* stateRow = states + ((size_t)(t - 1) * 64 + row_b) * 1024 - 64;
#pragma unroll 8
      for (int kt = 2; kt < 34; kt++) {
        int koff = kt * 32 + lq * 8;
        f16x8 a = *(const f16x8*)(stateRow + koff);
        f16x8 bb = *(const f16x8*)(&sW1[wrow * SW1S + koff]);
        acc[kt & 3] = MFMA16(a, bb, acc[kt & 3]);
      }
    }
    f32x4 r1 = (acc[0] + acc[1]) + (acc[2] + acc[3]);
#pragma unroll
    for (int rr = 0; rr < 4; rr++) {
      float v = r1[rr] + bias1;
      v = v > 0.f ? v : 0.f;
      int lb = mt * 16 + lq * 4 + rr;
      st_f16_wt(hG + ((size_t)t * 64 + r0 + lb) * 1056 + n0 + wrow, v);
    }
    asm volatile("s_waitcnt vmcnt(0)" ::: "memory");
    __syncthreads();
    if (tid == 0)
      __hip_atomic_fetch_add(&cnt[t * 2], 1u, __ATOMIC_RELAXED, __HIP_MEMORY_SCOPE_AGENT);

    // ---- GEMM2: out_slice = h @ Wd2_slice + bd2 ----
    if (j < 32) {
      if (tid == 0) {
        while (__hip_atomic_load(&cnt[t * 2], __ATOMIC_RELAXED,
                                 __HIP_MEMORY_SCOPE_AGENT) < 33u)
          __builtin_amdgcn_s_sleep(1);
      }
      __syncthreads();
      f32x4 acc2[4] = {};
      const f16* hRow = hG + ((size_t)t * 64 + row_b) * 1056;
#pragma unroll 8
      for (int kt = 0; kt < 33; kt++) {
        int koff = kt * 32 + lq * 8;
        f16x8 a = *(const f16x8*)(hRow + koff);
        f16x8 bb = *(const f16x8*)(&sW2[wrow * SW2S + koff]);
        acc2[kt & 3] = MFMA16(a, bb, acc2[kt & 3]);
      }
      f32x4 r2 = (acc2[0] + acc2[1]) + (acc2[2] + acc2[3]);
#pragma unroll
      for (int rr = 0; rr < 4; rr++) {
        int lb = mt * 16 + lq * 4 + rr;
        st_f16_wt(states + ((size_t)t * 64 + r0 + lb) * 1024 + n0 + wrow, r2[rr] + bias2);
      }
      asm volatile("s_waitcnt vmcnt(0)" ::: "memory");
      __syncthreads();
      if (tid == 0)
        __hip_atomic_fetch_add(&cnt[t * 2 + 1], 1u, __ATOMIC_RELAXED, __HIP_MEMORY_SCOPE_AGENT);
    }
  }
}

// =============================== output ===============================
__global__ __launch_bounds__(256) void k_out(const f16* __restrict__ states,
                                             float* __restrict__ out) {
  __shared__ float tile[32][33];
  int b = blockIdx.z, t0 = blockIdx.x * 32, s0 = blockIdx.y * 32;
  int r = threadIdx.x >> 3, c4 = (threadIdx.x & 7) * 4;
  f16x4 v = *(const f16x4*)(states + ((size_t)(t0 + r) * 64 + b) * 1024 + s0 + c4);
  tile[r][c4 + 0] = (float)v[0]; tile[r][c4 + 1] = (float)v[1];
  tile[r][c4 + 2] = (float)v[2]; tile[r][c4 + 3] = (float)v[3];
  __syncthreads();
  float4 o;
  o.x = tile[c4 + 0][r]; o.y = tile[c4 + 1][r];
  o.z = tile[c4 + 2][r]; o.w = tile[c4 + 3][r];
  *(float4*)(out + ((size_t)b * 1024 + s0 + r) * 256 + t0 + c4) = o;
}

// =============================== launch ===============================

extern "C" void kernel_launch(void* const* d_in, const int* in_sizes, int n_in,
                              void* d_out, int out_size, void* d_ws, size_t ws_size,
                              hipStream_t stream) {
  const float* x   = (const float*)d_in[0];
  const float* We1 = (const float*)d_in[1];
  const float* be1 = (const float*)d_in[2];
  const float* We2 = (const float*)d_in[3];
  const float* be2 = (const float*)d_in[4];
  const float* Wd1 = (const float*)d_in[5];
  const float* bd1 = (const float*)d_in[6];
  const float* Wd2 = (const float*)d_in[7];
  const float* bd2 = (const float*)d_in[8];
  float* outp = (float*)d_out;

  if (ws_size < WS_NEED) return;
  char* ws = (char*)d_ws;
  unsigned* flags = (unsigned*)(ws + OFF_FLAGS);
  f16* xT    = (f16*)(ws + OFF_XT);
  f16* We1T  = (f16*)(ws + OFF_WE1T);
  f16* We2T  = (f16*)(ws + OFF_WE2T);
  f16* Wd1T  = (f16*)(ws + OFF_WD1T);
  f16* Wd2T  = (f16*)(ws + OFF_WD2T);
  f16* Henc  = (f16*)(ws + OFF_HENC);
  f16* ctrl  = (f16*)(ws + OFF_CTRL);
  f16* st    = (f16*)(ws + OFF_ST);
  f16* hG    = Henc;  // decoder h exchange, t-indexed [256][64][1056], aliases Henc (dead after enc2)

  (void)hipMemsetAsync(flags, 0, 4096, stream);
  k_zero_x0<<<64, 256, 0, stream>>>(xT);
  k_transpose_x<<<dim3(32, 8, 64), 256, 0, stream>>>(x, xT);
  k_transpose_w<<<dim3(64, 36), 256, 0, stream>>>(We1, We1T, 2048, 1056, 2048, 1152);
  k_transpose_w<<<dim3(36, 2), 256, 0, stream>>>(We2, We2T, 1056, 64, 1152, 64);
  k_transpose_w<<<dim3(34, 33), 256, 0, stream>>>(Wd1, Wd1T, 1088, 1056, 1088, 1056);
  k_transpose_w<<<dim3(33, 32), 256, 0, stream>>>(Wd2, Wd2T, 1056, 1024, 1056, 1024);
  k_enc1<<<dim3(128, 9), 256, 0, stream>>>(xT, We1T, be1, Henc);
  k_enc2<<<128, 256, 0, stream>>>(Henc, We2T, be2, ctrl);
  (void)hipFuncSetAttribute((const void*)k_decoder, hipFuncAttributeMaxDynamicSharedMemorySize,
                            (int)DEC_LDS);
  k_decoder<<<66, 256, DEC_LDS, stream>>>(ctrl, Wd1T, Wd2T, bd1, bd2, st, hG, flags);
  k_out<<<dim3(8, 32, 64), 256, 0, stream>>>(st, outp);
}